// Round 7
// baseline (257.551 us; speedup 1.0000x reference)
//
#include <hip/hip_runtime.h>
#include <math.h>

#define NN 512
#define HH 64
#define NLAYERS 4
#define LN_EPS 1e-5f

typedef __attribute__((ext_vector_type(2))) float f32x2;

// ---------------------------------------------------------------------------
// 5-dispatch pipeline (validated algebra, absmax 0.0 in rounds 2-4):
//   k_pre      : blocks 0..1023  -> ea (src-major) to EAT (dst-major, padded
//                to 8 floats/src for b128 LDS reads + coalesced writes)
//                blocks 1024..1535 -> encoder MLP + layer-0 prep
//   k_layer x4 : edge phase (8 waves, dense softmax attention over 512 srcs)
//                + node phase + next-layer prep (double-buffered) ;
//                last layer fuses the decoder instead of prep.
// Score algebra: leaky(z)=0.6z+0.4|z|; dst-constant terms cancel in softmax;
// ea-linear term contracted to w6s[6]; src-linear part = Sq[i]; per-src
// linear score a_lin precomputed once into Sq_s.
// ---------------------------------------------------------------------------

__launch_bounds__(256)
__global__ void k_pre(const float* __restrict__ ea, const float* __restrict__ x,
                      const float* __restrict__ ew1, const float* __restrict__ eb1,
                      const float* __restrict__ ew2, const float* __restrict__ eb2,
                      const float* __restrict__ aw1, const float* __restrict__ ab1,
                      const float* __restrict__ wa2, const float* __restrict__ vw1,
                      const float* __restrict__ vb1,
                      float* __restrict__ EAT, float* __restrict__ h,
                      float* __restrict__ Pd, float* __restrict__ Qs,
                      float* __restrict__ Rv, float* __restrict__ Sq) {
    __shared__ float r1[HH], hs[HH];
    __shared__ float part[4][HH], partQ[4][HH], partR[4][HH];

    if (blockIdx.x < 1024) {
        // transpose+pad: EAT[(j*NN+i)*8 + k] = ea[(i*NN+j)*6 + k], k<6; pad=0
        int t = blockIdx.x * 256 + threadIdx.x;      // t = j*NN + i
        int i = t & (NN - 1);
        int j = t >> 9;
        const float2* s2 = (const float2*)(ea + ((size_t)i * NN + j) * 6);
        float2 e0 = s2[0], e1 = s2[1], e2 = s2[2];
        float4 a, b;
        a.x = e0.x; a.y = e0.y; a.z = e1.x; a.w = e1.y;
        b.x = e2.x; b.y = e2.y; b.z = 0.f; b.w = 0.f;
        float4* dst = (float4*)(EAT + (size_t)t * 8);
        dst[0] = a;
        dst[1] = b;
        return;
    }

    const int j = blockIdx.x - 1024;
    const int tid = threadIdx.x;
    const int d = tid & 63;
    const int w = tid >> 6;        // 0..3

    if (w == 0) {
        float z = eb1[d];
#pragma unroll
        for (int k = 0; k < 6; ++k) z += x[j * 6 + k] * ew1[k * HH + d];
        r1[d] = fmaxf(z, 0.f);
    }
    __syncthreads();
    {
        float z2 = (w == 0) ? eb2[d] : 0.f;
        for (int k = w * 16; k < w * 16 + 16; ++k) z2 += r1[k] * ew2[k * HH + d];
        part[w][d] = z2;
    }
    __syncthreads();
    if (w == 0) {
        float hv = part[0][d] + part[1][d] + part[2][d] + part[3][d];
        h[(size_t)j * HH + d] = hv;
        hs[d] = hv;
    }
    __syncthreads();
    {
        float pp = (w == 0) ? ab1[d] : 0.f;
        float qq = 0.f;
        float rr = (w == 0) ? vb1[d] : 0.f;
        for (int k = w * 16; k < w * 16 + 16; ++k) {
            float hk = hs[k];
            pp += hk * aw1[k * HH + d];
            qq += hk * aw1[(HH + k) * HH + d];
            rr += hk * vw1[k * HH + d];
        }
        part[w][d] = pp; partQ[w][d] = qq; partR[w][d] = rr;
    }
    __syncthreads();
    if (w == 0) {
        float qf = partQ[0][d] + partQ[1][d] + partQ[2][d] + partQ[3][d];
        Pd[(size_t)j * HH + d] = part[0][d] + part[1][d] + part[2][d] + part[3][d];
        Qs[(size_t)j * HH + d] = qf;
        Rv[(size_t)j * HH + d] = partR[0][d] + partR[1][d] + partR[2][d] + partR[3][d];
        float sq = qf * wa2[d];
#pragma unroll
        for (int o = 32; o; o >>= 1) sq += __shfl_xor(sq, o);
        if (d == 0) Sq[j] = sq;
    }
}

// Layer kernel: 512 threads = 8 waves, block j owns dst node j.
__launch_bounds__(512, 4)
__global__ void k_layer(const float* __restrict__ eat, const float* __restrict__ h_in,
                        const float* __restrict__ Pd, const float* __restrict__ Qs,
                        const float* __restrict__ Rv, const float* __restrict__ Sq,
                        const float* __restrict__ waE,   // att_w1[l] rows 128..133 (6x64)
                        const float* __restrict__ wa2v,  // att_w2[l] (64)
                        const float* __restrict__ wvE,   // val_w1[l] rows 64..69 (6x64)
                        const float* __restrict__ wv2, const float* __restrict__ vb2,
                        const float* __restrict__ uw1, const float* __restrict__ ub1,
                        const float* __restrict__ uw2, const float* __restrict__ ub2,
                        const float* __restrict__ lng, const float* __restrict__ lnb,
                        float* __restrict__ h_out,
                        const float* __restrict__ aw1n, const float* __restrict__ ab1n,
                        const float* __restrict__ wa2n, const float* __restrict__ vw1n,
                        const float* __restrict__ vb1n,
                        float* __restrict__ Pdn, float* __restrict__ Qsn,
                        float* __restrict__ Rvn, float* __restrict__ Sqn,
                        const float* __restrict__ dw1, const float* __restrict__ db1,
                        const float* __restrict__ dw2, const float* __restrict__ db2,
                        float* __restrict__ out,
                        int do_prep) {
    const int j = blockIdx.x;
    const int tid = threadIdx.x;
    const int lane = tid & 63;
    const int w = tid >> 6;        // wave 0..7
    const int slot = lane >> 3;    // 0..7 (src sub-index)
    const int dp = lane & 7;       // 0..7 (dim part)
    const int d0 = dp * 8;
    const int d = lane;

    __shared__ __align__(16) float ea_s[NN * 8];   // 16 KB (padded, b128 reads)
    __shared__ __align__(16) float Sq_s[NN];       // raw Sq then a_lin
    __shared__ float a_s[NN];
    __shared__ float red_m[8], red_s[8];
    __shared__ float accs[8][HH];
    __shared__ float av[HH], uin[2 * HH], r1[HH], hs[HH];
    __shared__ float part[8][HH], partQ[8][HH], partR[8][HH];

    // ---- stage: ea (coalesced, 1024 float4 over 512 threads), Sq ----
    {
        const float4* s4 = (const float4*)(eat + (size_t)j * (NN * 8));
        float4* d4 = (float4*)ea_s;
        d4[tid] = s4[tid];
        d4[tid + 512] = s4[tid + 512];
    }
    if (tid < 128) ((float4*)Sq_s)[tid] = ((const float4*)Sq)[tid];

    // ---- per-lane weight registers (f32x2-packed over the u dimension) ----
    f32x2 WA2[6][4], pdr2[4];
    float wa2raw[8], wa2r[8], w6s[6];
#pragma unroll
    for (int k = 0; k < 6; ++k)
#pragma unroll
        for (int p = 0; p < 4; ++p) {
            WA2[k][p].x = waE[k * HH + d0 + 2 * p];
            WA2[k][p].y = waE[k * HH + d0 + 2 * p + 1];
        }
#pragma unroll
    for (int u = 0; u < 8; ++u) wa2raw[u] = wa2v[d0 + u];
#pragma unroll
    for (int p = 0; p < 4; ++p) {
        pdr2[p].x = Pd[(size_t)j * HH + d0 + 2 * p];
        pdr2[p].y = Pd[(size_t)j * HH + d0 + 2 * p + 1];
    }
#pragma unroll
    for (int k = 0; k < 6; ++k) {
        float t = 0.f;
#pragma unroll
        for (int p = 0; p < 4; ++p) t += WA2[k][p].x * wa2raw[2 * p] + WA2[k][p].y * wa2raw[2 * p + 1];
        t += __shfl_xor(t, 1);
        t += __shfl_xor(t, 2);
        t += __shfl_xor(t, 4);
        w6s[k] = 0.6f * t;
    }
#pragma unroll
    for (int u = 0; u < 8; ++u) wa2r[u] = 0.4f * wa2raw[u];
    __syncthreads();

    // ---- precompute per-src linear score term into Sq_s (1 src per thread) ----
    {
        float alin = 0.6f * Sq_s[tid];
#pragma unroll
        for (int k = 0; k < 6; ++k) alin += ea_s[tid * 8 + k] * w6s[k];
        __syncthreads();
        Sq_s[tid] = alin;
    }
    __syncthreads();

    // ---- phase 1: scores for this wave's 64 srcs ----
    const int ibw = w * 64;
    float lmax = -1e30f;
#pragma unroll
    for (int it = 0; it < 8; ++it) {
        const int i = ibw + it * 8 + slot;
        const float4* q4 = (const float4*)(Qs + (size_t)i * HH + d0);
        float4 qa = q4[0], qb = q4[1];
        f32x2 qv2[4] = {{qa.x, qa.y}, {qa.z, qa.w}, {qb.x, qb.y}, {qb.z, qb.w}};
        const float4* e4 = (const float4*)(ea_s + i * 8);
        float4 ea0 = e4[0], ea1 = e4[1];
        float eav[6] = {ea0.x, ea0.y, ea0.z, ea0.w, ea1.x, ea1.y};
        float p1 = 0.f;
#pragma unroll
        for (int p = 0; p < 4; ++p) {
            f32x2 z = pdr2[p] + qv2[p];
#pragma unroll
            for (int k = 0; k < 6; ++k) z += WA2[k][p] * eav[k];
            p1 += fabsf(z.x) * wa2r[2 * p];
            p1 += fabsf(z.y) * wa2r[2 * p + 1];
        }
        p1 += __shfl_xor(p1, 1);
        p1 += __shfl_xor(p1, 2);
        p1 += __shfl_xor(p1, 4);
        float a = Sq_s[i] + p1;
        if (dp == 0) a_s[i] = a;
        lmax = fmaxf(lmax, a);
    }
#pragma unroll
    for (int o = 32; o; o >>= 1) lmax = fmaxf(lmax, __shfl_xor(lmax, o));
    if (lane == 0) red_m[w] = lmax;
    __syncthreads();
    float m = red_m[0];
#pragma unroll
    for (int q = 1; q < 8; ++q) m = fmaxf(m, red_m[q]);

    // ---- exp + sum (512 entries, 1 per thread) ----
    float e = expf(a_s[tid] - m);
    a_s[tid] = e;
    float lsum = e;
#pragma unroll
    for (int o = 32; o; o >>= 1) lsum += __shfl_xor(lsum, o);
    if (lane == 0) red_s[w] = lsum;
    __syncthreads();
    float s = red_s[0];
#pragma unroll
    for (int q = 1; q < 8; ++q) s += red_s[q];

    // ---- phase 2: weighted aggregate of relu(value-layer-1) ----
    f32x2 WV2[6][4];   // deferred load keeps phase-1 register pressure low
#pragma unroll
    for (int k = 0; k < 6; ++k)
#pragma unroll
        for (int p = 0; p < 4; ++p) {
            WV2[k][p].x = wvE[k * HH + d0 + 2 * p];
            WV2[k][p].y = wvE[k * HH + d0 + 2 * p + 1];
        }
    float acc[8] = {0.f, 0.f, 0.f, 0.f, 0.f, 0.f, 0.f, 0.f};
#pragma unroll
    for (int it = 0; it < 8; ++it) {
        const int i = ibw + it * 8 + slot;
        const float4* r4 = (const float4*)(Rv + (size_t)i * HH + d0);
        float4 ra = r4[0], rb = r4[1];
        f32x2 rv2[4] = {{ra.x, ra.y}, {ra.z, ra.w}, {rb.x, rb.y}, {rb.z, rb.w}};
        const float4* e4 = (const float4*)(ea_s + i * 8);
        float4 ea0 = e4[0], ea1 = e4[1];
        float eav[6] = {ea0.x, ea0.y, ea0.z, ea0.w, ea1.x, ea1.y};
        const float wi = a_s[i];
#pragma unroll
        for (int p = 0; p < 4; ++p) {
            f32x2 z = rv2[p];
#pragma unroll
            for (int k = 0; k < 6; ++k) z += WV2[k][p] * eav[k];
            acc[2 * p]     += wi * fmaxf(z.x, 0.f);
            acc[2 * p + 1] += wi * fmaxf(z.y, 0.f);
        }
    }
#pragma unroll
    for (int u = 0; u < 8; ++u) {
        acc[u] += __shfl_xor(acc[u], 8);
        acc[u] += __shfl_xor(acc[u], 16);
        acc[u] += __shfl_xor(acc[u], 32);
    }
    if (slot == 0) {
#pragma unroll
        for (int u = 0; u < 8; ++u) accs[w][d0 + u] = acc[u];
    }
    __syncthreads();
    if (tid < HH) {
        float tot = accs[0][tid];
#pragma unroll
        for (int q = 1; q < 8; ++q) tot += accs[q][tid];
        av[tid] = tot / s;
    }
    __syncthreads();

    // ---- node phase (split-K over 8 waves) ----
    const float hv = h_in[(size_t)j * HH + d];
    {
        float p = (w == 0) ? vb2[d] : 0.f;
        for (int k = w * 8; k < w * 8 + 8; ++k) p += av[k] * wv2[k * HH + d];
        part[w][d] = p;
        if (w == 0) uin[d] = hv;
    }
    __syncthreads();
    if (w == 0) {
        float agg = part[0][d];
#pragma unroll
        for (int q = 1; q < 8; ++q) agg += part[q][d];
        uin[HH + d] = agg;
    }
    __syncthreads();
    {
        float t = (w == 0) ? ub1[d] : 0.f;
        for (int c = w * 16; c < w * 16 + 16; ++c) t += uin[c] * uw1[c * HH + d];
        part[w][d] = t;
    }
    __syncthreads();
    if (w == 0) {
        float t = part[0][d];
#pragma unroll
        for (int q = 1; q < 8; ++q) t += part[q][d];
        r1[d] = fmaxf(t, 0.f);
    }
    __syncthreads();
    {
        float u = (w == 0) ? ub2[d] : 0.f;
        for (int k = w * 8; k < w * 8 + 8; ++k) u += r1[k] * uw2[k * HH + d];
        part[w][d] = u;
    }
    __syncthreads();
    if (w == 0) {
        float r = hv + part[0][d];
#pragma unroll
        for (int q = 1; q < 8; ++q) r += part[q][d];
        float sum = r;
#pragma unroll
        for (int o = 32; o; o >>= 1) sum += __shfl_xor(sum, o);
        float mu = sum * (1.f / HH);
        float dr = r - mu;
        float v2 = dr * dr;
#pragma unroll
        for (int o = 32; o; o >>= 1) v2 += __shfl_xor(v2, o);
        float var = v2 * (1.f / HH);
        float hn = lng[d] * dr * (1.f / sqrtf(var + LN_EPS)) + lnb[d];
        h_out[(size_t)j * HH + d] = hn;
        hs[d] = hn;
    }
    __syncthreads();

    if (do_prep) {
        // next-layer prep into the other buffer set
        float pp = (w == 0) ? ab1n[d] : 0.f;
        float qq = 0.f;
        float rr = (w == 0) ? vb1n[d] : 0.f;
        for (int k = w * 8; k < w * 8 + 8; ++k) {
            float hk = hs[k];
            pp += hk * aw1n[k * HH + d];
            qq += hk * aw1n[(HH + k) * HH + d];
            rr += hk * vw1n[k * HH + d];
        }
        part[w][d] = pp; partQ[w][d] = qq; partR[w][d] = rr;
        __syncthreads();
        if (w == 0) {
            float pf = part[0][d], qf = partQ[0][d], rf = partR[0][d];
#pragma unroll
            for (int q = 1; q < 8; ++q) {
                pf += part[q][d]; qf += partQ[q][d]; rf += partR[q][d];
            }
            Pdn[(size_t)j * HH + d] = pf;
            Qsn[(size_t)j * HH + d] = qf;
            Rvn[(size_t)j * HH + d] = rf;
            float sq = qf * wa2n[d];
#pragma unroll
            for (int o = 32; o; o >>= 1) sq += __shfl_xor(sq, o);
            if (d == 0) Sqn[j] = sq;
        }
    } else {
        // fused decoder: out[j] = relu(hs@dw1+db1)@dw2 + db2
        float t = (w == 0) ? db1[d] : 0.f;
        for (int k = w * 8; k < w * 8 + 8; ++k) t += hs[k] * dw1[k * HH + d];
        part[w][d] = t;
        __syncthreads();
        if (w == 0) {
            float tt = part[0][d];
#pragma unroll
            for (int q = 1; q < 8; ++q) tt += part[q][d];
            tt = fmaxf(tt, 0.f);
            float sum = tt * dw2[d];
#pragma unroll
            for (int o = 32; o; o >>= 1) sum += __shfl_xor(sum, o);
            if (d == 0) out[j] = sum + db2[0];
        }
    }
}

extern "C" void kernel_launch(void* const* d_in, const int* in_sizes, int n_in,
                              void* d_out, int out_size, void* d_ws, size_t ws_size,
                              hipStream_t stream) {
    const float* x      = (const float*)d_in[0];
    const float* ea     = (const float*)d_in[1];
    const float* enc_w1 = (const float*)d_in[2];
    const float* enc_b1 = (const float*)d_in[3];
    const float* enc_w2 = (const float*)d_in[4];
    const float* enc_b2 = (const float*)d_in[5];
    const float* att_w1 = (const float*)d_in[6];
    const float* att_b1 = (const float*)d_in[7];
    const float* att_w2 = (const float*)d_in[8];
    // d_in[9] = att_b2: per-layer constant, cancels in softmax — unused
    const float* val_w1 = (const float*)d_in[10];
    const float* val_b1 = (const float*)d_in[11];
    const float* val_w2 = (const float*)d_in[12];
    const float* val_b2 = (const float*)d_in[13];
    const float* upd_w1 = (const float*)d_in[14];
    const float* upd_b1 = (const float*)d_in[15];
    const float* upd_w2 = (const float*)d_in[16];
    const float* upd_b2 = (const float*)d_in[17];
    const float* ln_g   = (const float*)d_in[18];
    const float* ln_b   = (const float*)d_in[19];
    const float* dec_w1 = (const float*)d_in[20];
    const float* dec_b1 = (const float*)d_in[21];
    const float* dec_w2 = (const float*)d_in[22];
    const float* dec_b2 = (const float*)d_in[23];
    // d_in[24] = edge_index: dense regular grid (src=e/N, dst=e%N) — used structurally

    const size_t NH = (size_t)NN * HH;
    float* ws   = (float*)d_ws;
    float* EAT  = ws;                              // NN*NN*8 (padded)
    float* h0   = EAT + (size_t)NN * NN * 8;
    float* h1   = h0 + NH;
    float* Pd0  = h1 + NH;
    float* Pd1  = Pd0 + NH;
    float* Qs0  = Pd1 + NH;
    float* Qs1  = Qs0 + NH;
    float* Rv0  = Qs1 + NH;
    float* Rv1  = Rv0 + NH;
    float* Sq0  = Rv1 + NH;
    float* Sq1  = Sq0 + NN;

    float* Pdb[2] = {Pd0, Pd1};
    float* Qsb[2] = {Qs0, Qs1};
    float* Rvb[2] = {Rv0, Rv1};
    float* Sqb[2] = {Sq0, Sq1};
    float* hb[2]  = {h0, h1};

    k_pre<<<1536, 256, 0, stream>>>(ea, x, enc_w1, enc_b1, enc_w2, enc_b2,
                                    att_w1, att_b1, att_w2, val_w1, val_b1,
                                    EAT, h0, Pd0, Qs0, Rv0, Sq0);

    for (int l = 0; l < NLAYERS; ++l) {
        const int cur = l & 1, nxt = (l + 1) & 1;
        const int np = (l + 1 < NLAYERS) ? (l + 1) : l;   // clamped; unused if do_prep=0
        const float* aw1 = att_w1 + (size_t)l * 134 * HH;
        const float* vw1 = val_w1 + (size_t)l * 70 * HH;
        k_layer<<<NN, 512, 0, stream>>>(
            EAT, hb[cur],
            Pdb[cur], Qsb[cur], Rvb[cur], Sqb[cur],
            aw1 + 128 * HH, att_w2 + l * HH, vw1 + 64 * HH,
            val_w2 + (size_t)l * HH * HH, val_b2 + l * HH,
            upd_w1 + (size_t)l * 2 * HH * HH, upd_b1 + l * HH,
            upd_w2 + (size_t)l * HH * HH, upd_b2 + l * HH,
            ln_g + l * HH, ln_b + l * HH,
            hb[nxt],
            att_w1 + (size_t)np * 134 * HH, att_b1 + np * HH, att_w2 + np * HH,
            val_w1 + (size_t)np * 70 * HH, val_b1 + np * HH,
            Pdb[nxt], Qsb[nxt], Rvb[nxt], Sqb[nxt],
            dec_w1, dec_b1, dec_w2, dec_b2, (float*)d_out,
            (l + 1 < NLAYERS) ? 1 : 0);
    }
}

// Round 8
// 209.426 us; speedup vs baseline: 1.2298x; 1.2298x over previous
//
#include <hip/hip_runtime.h>
#include <math.h>

#define NN 512
#define HH 64
#define NLAYERS 4
#define LN_EPS 1e-5f

// ---------------------------------------------------------------------------
// 5-dispatch pipeline (validated algebra, absmax 0.0 in rounds 2-4,7):
//   k_pre      : blocks 0..1023  -> ea (src-major) to EAT (dst-major, padded
//                to 8 floats/src for b128 LDS reads + coalesced writes)
//                blocks 1024..1535 -> encoder MLP + layer-0 prep
//   k_layer x4 : edge phase (8 waves, dense softmax attention over 512 srcs)
//                + node phase + next-layer prep (double-buffered);
//                last layer fuses the decoder instead of prep.
// Score algebra: leaky(z)=0.6z+0.4|z|; dst-constant terms cancel in softmax;
// ea-linear term contracted to w6s[6]; src-linear part = Sq[i]; per-src
// linear score a_lin precomputed once into Sq_s.
// NOTE (round 7 lesson): inner-loop operands MUST be scalar float arrays with
// fully static indices — f32x2 ext-vector arrays went to scratch (VGPR=64,
// 35 MB/dispatch spill writes, 2x slowdown). Keep scalar.
// ---------------------------------------------------------------------------

__launch_bounds__(256)
__global__ void k_pre(const float* __restrict__ ea, const float* __restrict__ x,
                      const float* __restrict__ ew1, const float* __restrict__ eb1,
                      const float* __restrict__ ew2, const float* __restrict__ eb2,
                      const float* __restrict__ aw1, const float* __restrict__ ab1,
                      const float* __restrict__ wa2, const float* __restrict__ vw1,
                      const float* __restrict__ vb1,
                      float* __restrict__ EAT, float* __restrict__ h,
                      float* __restrict__ Pd, float* __restrict__ Qs,
                      float* __restrict__ Rv, float* __restrict__ Sq) {
    __shared__ float r1[HH], hs[HH];
    __shared__ float part[4][HH], partQ[4][HH], partR[4][HH];

    if (blockIdx.x < 1024) {
        // transpose+pad: EAT[(j*NN+i)*8 + k] = ea[(i*NN+j)*6 + k], k<6; pad=0
        int t = blockIdx.x * 256 + threadIdx.x;      // t = j*NN + i
        int i = t & (NN - 1);
        int j = t >> 9;
        const float2* s2 = (const float2*)(ea + ((size_t)i * NN + j) * 6);
        float2 e0 = s2[0], e1 = s2[1], e2 = s2[2];
        float4 a, b;
        a.x = e0.x; a.y = e0.y; a.z = e1.x; a.w = e1.y;
        b.x = e2.x; b.y = e2.y; b.z = 0.f; b.w = 0.f;
        float4* dst = (float4*)(EAT + (size_t)t * 8);
        dst[0] = a;
        dst[1] = b;
        return;
    }

    const int j = blockIdx.x - 1024;
    const int tid = threadIdx.x;
    const int d = tid & 63;
    const int w = tid >> 6;        // 0..3

    if (w == 0) {
        float z = eb1[d];
#pragma unroll
        for (int k = 0; k < 6; ++k) z += x[j * 6 + k] * ew1[k * HH + d];
        r1[d] = fmaxf(z, 0.f);
    }
    __syncthreads();
    {
        float z2 = (w == 0) ? eb2[d] : 0.f;
        for (int k = w * 16; k < w * 16 + 16; ++k) z2 += r1[k] * ew2[k * HH + d];
        part[w][d] = z2;
    }
    __syncthreads();
    if (w == 0) {
        float hv = part[0][d] + part[1][d] + part[2][d] + part[3][d];
        h[(size_t)j * HH + d] = hv;
        hs[d] = hv;
    }
    __syncthreads();
    {
        float pp = (w == 0) ? ab1[d] : 0.f;
        float qq = 0.f;
        float rr = (w == 0) ? vb1[d] : 0.f;
        for (int k = w * 16; k < w * 16 + 16; ++k) {
            float hk = hs[k];
            pp += hk * aw1[k * HH + d];
            qq += hk * aw1[(HH + k) * HH + d];
            rr += hk * vw1[k * HH + d];
        }
        part[w][d] = pp; partQ[w][d] = qq; partR[w][d] = rr;
    }
    __syncthreads();
    if (w == 0) {
        float qf = partQ[0][d] + partQ[1][d] + partQ[2][d] + partQ[3][d];
        Pd[(size_t)j * HH + d] = part[0][d] + part[1][d] + part[2][d] + part[3][d];
        Qs[(size_t)j * HH + d] = qf;
        Rv[(size_t)j * HH + d] = partR[0][d] + partR[1][d] + partR[2][d] + partR[3][d];
        float sq = qf * wa2[d];
#pragma unroll
        for (int o = 32; o; o >>= 1) sq += __shfl_xor(sq, o);
        if (d == 0) Sq[j] = sq;
    }
}

// Layer kernel: 512 threads = 8 waves, block j owns dst node j.
__launch_bounds__(512, 4)
__global__ void k_layer(const float* __restrict__ eat, const float* __restrict__ h_in,
                        const float* __restrict__ Pd, const float* __restrict__ Qs,
                        const float* __restrict__ Rv, const float* __restrict__ Sq,
                        const float* __restrict__ waE,   // att_w1[l] rows 128..133 (6x64)
                        const float* __restrict__ wa2v,  // att_w2[l] (64)
                        const float* __restrict__ wvE,   // val_w1[l] rows 64..69 (6x64)
                        const float* __restrict__ wv2, const float* __restrict__ vb2,
                        const float* __restrict__ uw1, const float* __restrict__ ub1,
                        const float* __restrict__ uw2, const float* __restrict__ ub2,
                        const float* __restrict__ lng, const float* __restrict__ lnb,
                        float* __restrict__ h_out,
                        const float* __restrict__ aw1n, const float* __restrict__ ab1n,
                        const float* __restrict__ wa2n, const float* __restrict__ vw1n,
                        const float* __restrict__ vb1n,
                        float* __restrict__ Pdn, float* __restrict__ Qsn,
                        float* __restrict__ Rvn, float* __restrict__ Sqn,
                        const float* __restrict__ dw1, const float* __restrict__ db1,
                        const float* __restrict__ dw2, const float* __restrict__ db2,
                        float* __restrict__ out,
                        int do_prep) {
    const int j = blockIdx.x;
    const int tid = threadIdx.x;
    const int lane = tid & 63;
    const int w = tid >> 6;        // wave 0..7
    const int slot = lane >> 3;    // 0..7 (src sub-index)
    const int dp = lane & 7;       // 0..7 (dim part)
    const int d0 = dp * 8;
    const int d = lane;

    __shared__ __align__(16) float ea_s[NN * 8];   // 16 KB (padded, b128 reads)
    __shared__ __align__(16) float Sq_s[NN];       // raw Sq then a_lin
    __shared__ float a_s[NN];
    __shared__ float red_m[8], red_s[8];
    __shared__ float accs[8][HH];
    __shared__ float av[HH], uin[2 * HH], r1[HH], hs[HH];
    __shared__ float part[8][HH], partQ[8][HH], partR[8][HH];

    // ---- stage: ea (coalesced, 1024 float4 over 512 threads), Sq ----
    {
        const float4* s4 = (const float4*)(eat + (size_t)j * (NN * 8));
        float4* d4 = (float4*)ea_s;
        d4[tid] = s4[tid];
        d4[tid + 512] = s4[tid + 512];
    }
    if (tid < 128) ((float4*)Sq_s)[tid] = ((const float4*)Sq)[tid];

    // ---- per-lane weight registers (scalar arrays, static indices only) ----
    float WA[6][8], wa2raw[8], wa2r[8], pdr[8], w6s[6];
#pragma unroll
    for (int k = 0; k < 6; ++k)
#pragma unroll
        for (int u = 0; u < 8; ++u) WA[k][u] = waE[k * HH + d0 + u];
#pragma unroll
    for (int u = 0; u < 8; ++u) {
        wa2raw[u] = wa2v[d0 + u];
        pdr[u] = Pd[(size_t)j * HH + d0 + u];
    }
#pragma unroll
    for (int k = 0; k < 6; ++k) {
        float t = 0.f;
#pragma unroll
        for (int u = 0; u < 8; ++u) t += WA[k][u] * wa2raw[u];
        t += __shfl_xor(t, 1);
        t += __shfl_xor(t, 2);
        t += __shfl_xor(t, 4);
        w6s[k] = 0.6f * t;
    }
#pragma unroll
    for (int u = 0; u < 8; ++u) wa2r[u] = 0.4f * wa2raw[u];
    __syncthreads();

    // ---- precompute per-src linear score term into Sq_s (1 src per thread) ----
    {
        float alin = 0.6f * Sq_s[tid];
#pragma unroll
        for (int k = 0; k < 6; ++k) alin += ea_s[tid * 8 + k] * w6s[k];
        __syncthreads();
        Sq_s[tid] = alin;
    }
    __syncthreads();

    // ---- phase 1: scores for this wave's 64 srcs ----
    const int ibw = w * 64;
    float lmax = -1e30f;
#pragma unroll
    for (int it = 0; it < 8; ++it) {
        const int i = ibw + it * 8 + slot;
        const float4* q4 = (const float4*)(Qs + (size_t)i * HH + d0);
        float4 qa = q4[0], qb = q4[1];
        float qv[8] = {qa.x, qa.y, qa.z, qa.w, qb.x, qb.y, qb.z, qb.w};
        const float4* e4 = (const float4*)(ea_s + i * 8);
        float4 ea0 = e4[0], ea1 = e4[1];
        float eav[6] = {ea0.x, ea0.y, ea0.z, ea0.w, ea1.x, ea1.y};
        float p1 = 0.f;
#pragma unroll
        for (int u = 0; u < 8; ++u) {
            float z = pdr[u] + qv[u];
#pragma unroll
            for (int k = 0; k < 6; ++k) z += eav[k] * WA[k][u];
            p1 += fabsf(z) * wa2r[u];
        }
        p1 += __shfl_xor(p1, 1);
        p1 += __shfl_xor(p1, 2);
        p1 += __shfl_xor(p1, 4);
        float a = Sq_s[i] + p1;
        if (dp == 0) a_s[i] = a;
        lmax = fmaxf(lmax, a);
    }
#pragma unroll
    for (int o = 32; o; o >>= 1) lmax = fmaxf(lmax, __shfl_xor(lmax, o));
    if (lane == 0) red_m[w] = lmax;
    __syncthreads();
    float m = red_m[0];
#pragma unroll
    for (int q = 1; q < 8; ++q) m = fmaxf(m, red_m[q]);

    // ---- exp + sum (512 entries, 1 per thread) ----
    float e = expf(a_s[tid] - m);
    a_s[tid] = e;
    float lsum = e;
#pragma unroll
    for (int o = 32; o; o >>= 1) lsum += __shfl_xor(lsum, o);
    if (lane == 0) red_s[w] = lsum;
    __syncthreads();
    float s = red_s[0];
#pragma unroll
    for (int q = 1; q < 8; ++q) s += red_s[q];

    // ---- phase 2: weighted aggregate of relu(value-layer-1) ----
    float WV[6][8];   // deferred load keeps phase-1 register pressure low
#pragma unroll
    for (int k = 0; k < 6; ++k)
#pragma unroll
        for (int u = 0; u < 8; ++u) WV[k][u] = wvE[k * HH + d0 + u];
    float acc[8] = {0.f, 0.f, 0.f, 0.f, 0.f, 0.f, 0.f, 0.f};
#pragma unroll
    for (int it = 0; it < 8; ++it) {
        const int i = ibw + it * 8 + slot;
        const float4* r4 = (const float4*)(Rv + (size_t)i * HH + d0);
        float4 ra = r4[0], rb = r4[1];
        float rv[8] = {ra.x, ra.y, ra.z, ra.w, rb.x, rb.y, rb.z, rb.w};
        const float4* e4 = (const float4*)(ea_s + i * 8);
        float4 ea0 = e4[0], ea1 = e4[1];
        float eav[6] = {ea0.x, ea0.y, ea0.z, ea0.w, ea1.x, ea1.y};
        const float wi = a_s[i];
#pragma unroll
        for (int u = 0; u < 8; ++u) {
            float z = rv[u];
#pragma unroll
            for (int k = 0; k < 6; ++k) z += eav[k] * WV[k][u];
            acc[u] += wi * fmaxf(z, 0.f);
        }
    }
#pragma unroll
    for (int u = 0; u < 8; ++u) {
        acc[u] += __shfl_xor(acc[u], 8);
        acc[u] += __shfl_xor(acc[u], 16);
        acc[u] += __shfl_xor(acc[u], 32);
    }
    if (slot == 0) {
#pragma unroll
        for (int u = 0; u < 8; ++u) accs[w][d0 + u] = acc[u];
    }
    __syncthreads();
    if (tid < HH) {
        float tot = accs[0][tid];
#pragma unroll
        for (int q = 1; q < 8; ++q) tot += accs[q][tid];
        av[tid] = tot / s;
    }
    __syncthreads();

    // ---- node phase (split-K over 8 waves) ----
    const float hv = h_in[(size_t)j * HH + d];
    {
        float p = (w == 0) ? vb2[d] : 0.f;
        for (int k = w * 8; k < w * 8 + 8; ++k) p += av[k] * wv2[k * HH + d];
        part[w][d] = p;
        if (w == 0) uin[d] = hv;
    }
    __syncthreads();
    if (w == 0) {
        float agg = part[0][d];
#pragma unroll
        for (int q = 1; q < 8; ++q) agg += part[q][d];
        uin[HH + d] = agg;
    }
    __syncthreads();
    {
        float t = (w == 0) ? ub1[d] : 0.f;
        for (int c = w * 16; c < w * 16 + 16; ++c) t += uin[c] * uw1[c * HH + d];
        part[w][d] = t;
    }
    __syncthreads();
    if (w == 0) {
        float t = part[0][d];
#pragma unroll
        for (int q = 1; q < 8; ++q) t += part[q][d];
        r1[d] = fmaxf(t, 0.f);
    }
    __syncthreads();
    {
        float u = (w == 0) ? ub2[d] : 0.f;
        for (int k = w * 8; k < w * 8 + 8; ++k) u += r1[k] * uw2[k * HH + d];
        part[w][d] = u;
    }
    __syncthreads();
    if (w == 0) {
        float r = hv + part[0][d];
#pragma unroll
        for (int q = 1; q < 8; ++q) r += part[q][d];
        float sum = r;
#pragma unroll
        for (int o = 32; o; o >>= 1) sum += __shfl_xor(sum, o);
        float mu = sum * (1.f / HH);
        float dr = r - mu;
        float v2 = dr * dr;
#pragma unroll
        for (int o = 32; o; o >>= 1) v2 += __shfl_xor(v2, o);
        float var = v2 * (1.f / HH);
        float hn = lng[d] * dr * (1.f / sqrtf(var + LN_EPS)) + lnb[d];
        h_out[(size_t)j * HH + d] = hn;
        hs[d] = hn;
    }
    __syncthreads();

    if (do_prep) {
        // next-layer prep into the other buffer set
        float pp = (w == 0) ? ab1n[d] : 0.f;
        float qq = 0.f;
        float rr = (w == 0) ? vb1n[d] : 0.f;
        for (int k = w * 8; k < w * 8 + 8; ++k) {
            float hk = hs[k];
            pp += hk * aw1n[k * HH + d];
            qq += hk * aw1n[(HH + k) * HH + d];
            rr += hk * vw1n[k * HH + d];
        }
        part[w][d] = pp; partQ[w][d] = qq; partR[w][d] = rr;
        __syncthreads();
        if (w == 0) {
            float pf = part[0][d], qf = partQ[0][d], rf = partR[0][d];
#pragma unroll
            for (int q = 1; q < 8; ++q) {
                pf += part[q][d]; qf += partQ[q][d]; rf += partR[q][d];
            }
            Pdn[(size_t)j * HH + d] = pf;
            Qsn[(size_t)j * HH + d] = qf;
            Rvn[(size_t)j * HH + d] = rf;
            float sq = qf * wa2n[d];
#pragma unroll
            for (int o = 32; o; o >>= 1) sq += __shfl_xor(sq, o);
            if (d == 0) Sqn[j] = sq;
        }
    } else {
        // fused decoder: out[j] = relu(hs@dw1+db1)@dw2 + db2
        float t = (w == 0) ? db1[d] : 0.f;
        for (int k = w * 8; k < w * 8 + 8; ++k) t += hs[k] * dw1[k * HH + d];
        part[w][d] = t;
        __syncthreads();
        if (w == 0) {
            float tt = part[0][d];
#pragma unroll
            for (int q = 1; q < 8; ++q) tt += part[q][d];
            tt = fmaxf(tt, 0.f);
            float sum = tt * dw2[d];
#pragma unroll
            for (int o = 32; o; o >>= 1) sum += __shfl_xor(sum, o);
            if (d == 0) out[j] = sum + db2[0];
        }
    }
}

extern "C" void kernel_launch(void* const* d_in, const int* in_sizes, int n_in,
                              void* d_out, int out_size, void* d_ws, size_t ws_size,
                              hipStream_t stream) {
    const float* x      = (const float*)d_in[0];
    const float* ea     = (const float*)d_in[1];
    const float* enc_w1 = (const float*)d_in[2];
    const float* enc_b1 = (const float*)d_in[3];
    const float* enc_w2 = (const float*)d_in[4];
    const float* enc_b2 = (const float*)d_in[5];
    const float* att_w1 = (const float*)d_in[6];
    const float* att_b1 = (const float*)d_in[7];
    const float* att_w2 = (const float*)d_in[8];
    // d_in[9] = att_b2: per-layer constant, cancels in softmax — unused
    const float* val_w1 = (const float*)d_in[10];
    const float* val_b1 = (const float*)d_in[11];
    const float* val_w2 = (const float*)d_in[12];
    const float* val_b2 = (const float*)d_in[13];
    const float* upd_w1 = (const float*)d_in[14];
    const float* upd_b1 = (const float*)d_in[15];
    const float* upd_w2 = (const float*)d_in[16];
    const float* upd_b2 = (const float*)d_in[17];
    const float* ln_g   = (const float*)d_in[18];
    const float* ln_b   = (const float*)d_in[19];
    const float* dec_w1 = (const float*)d_in[20];
    const float* dec_b1 = (const float*)d_in[21];
    const float* dec_w2 = (const float*)d_in[22];
    const float* dec_b2 = (const float*)d_in[23];
    // d_in[24] = edge_index: dense regular grid (src=e/N, dst=e%N) — used structurally

    const size_t NH = (size_t)NN * HH;
    float* ws   = (float*)d_ws;
    float* EAT  = ws;                              // NN*NN*8 (padded)
    float* h0   = EAT + (size_t)NN * NN * 8;
    float* h1   = h0 + NH;
    float* Pd0  = h1 + NH;
    float* Pd1  = Pd0 + NH;
    float* Qs0  = Pd1 + NH;
    float* Qs1  = Qs0 + NH;
    float* Rv0  = Qs1 + NH;
    float* Rv1  = Rv0 + NH;
    float* Sq0  = Rv1 + NH;
    float* Sq1  = Sq0 + NN;

    float* Pdb[2] = {Pd0, Pd1};
    float* Qsb[2] = {Qs0, Qs1};
    float* Rvb[2] = {Rv0, Rv1};
    float* Sqb[2] = {Sq0, Sq1};
    float* hb[2]  = {h0, h1};

    k_pre<<<1536, 256, 0, stream>>>(ea, x, enc_w1, enc_b1, enc_w2, enc_b2,
                                    att_w1, att_b1, att_w2, val_w1, val_b1,
                                    EAT, h0, Pd0, Qs0, Rv0, Sq0);

    for (int l = 0; l < NLAYERS; ++l) {
        const int cur = l & 1, nxt = (l + 1) & 1;
        const int np = (l + 1 < NLAYERS) ? (l + 1) : l;   // clamped; unused if do_prep=0
        const float* aw1 = att_w1 + (size_t)l * 134 * HH;
        const float* vw1 = val_w1 + (size_t)l * 70 * HH;
        k_layer<<<NN, 512, 0, stream>>>(
            EAT, hb[cur],
            Pdb[cur], Qsb[cur], Rvb[cur], Sqb[cur],
            aw1 + 128 * HH, att_w2 + l * HH, vw1 + 64 * HH,
            val_w2 + (size_t)l * HH * HH, val_b2 + l * HH,
            upd_w1 + (size_t)l * 2 * HH * HH, upd_b1 + l * HH,
            upd_w2 + (size_t)l * HH * HH, upd_b2 + l * HH,
            ln_g + l * HH, ln_b + l * HH,
            hb[nxt],
            att_w1 + (size_t)np * 134 * HH, att_b1 + np * HH, att_w2 + np * HH,
            val_w1 + (size_t)np * 70 * HH, val_b1 + np * HH,
            Pdb[nxt], Qsb[nxt], Rvb[nxt], Sqb[nxt],
            dec_w1, dec_b1, dec_w2, dec_b2, (float*)d_out,
            (l + 1 < NLAYERS) ? 1 : 0);
    }
}